// Round 1
// baseline (3629.756 us; speedup 1.0000x reference)
//
#include <hip/hip_runtime.h>

#define S_LEN 2048
#define H_DIM 1536
#define NQ_H 12
#define NKV_H 2
#define HD 128
#define I_DIM 8960
#define QKV_N 2048
#define GU_N 17920
#define SCALE 0.08838834764831845f

typedef _Float16 f16;
typedef _Float16 f16x8 __attribute__((ext_vector_type(8)));
typedef float f32x4 __attribute__((ext_vector_type(4)));

__device__ __forceinline__ void gload16(const void* g, void* l) {
  __builtin_amdgcn_global_load_lds((__attribute__((address_space(1))) void*)g,
                                   (__attribute__((address_space(3))) void*)l,
                                   16, 0, 0);
}

// ---------------- GEMM 256x256 tile, BK=32, 4-deep LDS ring, counted vmcnt ----------------
// C[M,N](+)= A[M,K] (f16) @ BT[N,K]^T (f16). Split-K via blockIdx.z (range Kc).
// MODE 1: unsafeAtomicAdd into Cf (f32). MODE 2: Ch = acc (f16; requires gridDim.z==1).
// LDS chunk swizzle: cell(row, x) holds logical k-chunk x ^ s(row), s(row)=(row&3)^((row>>2)&1).
// global_load_lds dest stays linear (rule 21): the source address is pre-swizzled instead.
template <int MODE>
__global__ __launch_bounds__(512, 2) void gemm256(const f16* __restrict__ A,
                                                  const f16* __restrict__ BT,
                                                  float* __restrict__ Cf,
                                                  f16* __restrict__ Ch,
                                                  int N, int Ktot, int Kc) {
  constexpr int TE = 256 * 32;  // f16 elems per ring slot (one 256x32 tile)
  __shared__ __attribute__((aligned(16))) f16 As[4 * TE];
  __shared__ __attribute__((aligned(16))) f16 Bs[4 * TE];
  const int tid = threadIdx.x;
  const int w = tid >> 6, lane = tid & 63;
  const int quad = lane >> 4, cc = lane & 15;
  const int wm = w >> 2, wn = w & 3;  // 2 (M) x 4 (N) waves; per-wave 128x64 output
  const int m0 = blockIdx.y * 256, n0 = blockIdx.x * 256;
  const int kbase = blockIdx.z * Kc;
  const int NT = Kc >> 5;

  // staging: per tile each wave loads 4 x (64 lanes x 16B): A rows [w*16,+16) and
  // [128+w*16,+16), same for B. LDS dest linear; global k-chunk pre-swizzled.
  const int lr = lane >> 2, lc = lane & 3;
  const int cg = lc ^ (lr & 3) ^ ((lr >> 2) & 1);
  const f16* AgR0 = A + (size_t)(m0 + w * 16 + lr) * Ktot + kbase + cg * 8;
  const f16* AgR1 = AgR0 + (size_t)128 * Ktot;
  const f16* BgR0 = BT + (size_t)(n0 + w * 16 + lr) * Ktot + kbase + cg * 8;
  const f16* BgR1 = BgR0 + (size_t)128 * Ktot;
  const int ldsl0 = (w * 16) * 32;
  const int ldsl1 = (128 + w * 16) * 32;

  // swizzled read chunk (logical chunk = quad): row == cc (mod 16)
  const int sc8 = (quad ^ (cc & 3) ^ ((cc >> 2) & 1)) * 8;

  const f32x4 fz = {0.f, 0.f, 0.f, 0.f};
  f32x4 acc[8][4];
#pragma unroll
  for (int i = 0; i < 8; ++i)
#pragma unroll
    for (int j = 0; j < 4; ++j) acc[i][j] = fz;

  // prologue: issue tiles 0..2 (12 loads/wave, FIFO)
#pragma unroll
  for (int pt = 0; pt < 3; ++pt) {
    const int kk = pt * 32;
    gload16(AgR0 + kk, As + pt * TE + ldsl0);
    gload16(AgR1 + kk, As + pt * TE + ldsl1);
    gload16(BgR0 + kk, Bs + pt * TE + ldsl0);
    gload16(BgR1 + kk, Bs + pt * TE + ldsl1);
  }

  for (int t = 0; t < NT; ++t) {
    const f16* Ab = As + (t & 3) * TE;
    const f16* Bb = Bs + (t & 3) * TE;
    // counted wait: tiles t+1,t+2 may stay in flight (4 loads each per wave)
    const int ahead = NT - 1 - t;
    if (ahead >= 2)      asm volatile("s_waitcnt vmcnt(8)" ::: "memory");
    else if (ahead == 1) asm volatile("s_waitcnt vmcnt(4)" ::: "memory");
    else                 asm volatile("s_waitcnt vmcnt(0)" ::: "memory");
    asm volatile("s_barrier" ::: "memory");

    const bool pf = (t + 3) < NT;
    const int kq = (t + 3) * 32;
    f16* Apf = As + ((t + 3) & 3) * TE;
    f16* Bpf = Bs + ((t + 3) & 3) * TE;

    f16x8 bf[4], af0, af1;

    // ---- sub-phase 0: B frags + A rows 0,1 ----
    if (pf) gload16(AgR0 + kq, Apf + ldsl0);
#pragma unroll
    for (int fc = 0; fc < 4; ++fc)
      bf[fc] = *(const f16x8*)(Bb + (wn * 64 + fc * 16 + cc) * 32 + sc8);
    af0 = *(const f16x8*)(Ab + (wm * 128 + 0 * 16 + cc) * 32 + sc8);
    af1 = *(const f16x8*)(Ab + (wm * 128 + 1 * 16 + cc) * 32 + sc8);
#pragma unroll
    for (int fc = 0; fc < 4; ++fc)
      acc[0][fc] = __builtin_amdgcn_mfma_f32_16x16x32_f16(af0, bf[fc], acc[0][fc], 0, 0, 0);
#pragma unroll
    for (int fc = 0; fc < 4; ++fc)
      acc[1][fc] = __builtin_amdgcn_mfma_f32_16x16x32_f16(af1, bf[fc], acc[1][fc], 0, 0, 0);
    asm volatile("s_barrier" ::: "memory");

    // ---- sub-phase 1: A rows 2,3 ----
    if (pf) gload16(AgR1 + kq, Apf + ldsl1);
    af0 = *(const f16x8*)(Ab + (wm * 128 + 2 * 16 + cc) * 32 + sc8);
    af1 = *(const f16x8*)(Ab + (wm * 128 + 3 * 16 + cc) * 32 + sc8);
#pragma unroll
    for (int fc = 0; fc < 4; ++fc)
      acc[2][fc] = __builtin_amdgcn_mfma_f32_16x16x32_f16(af0, bf[fc], acc[2][fc], 0, 0, 0);
#pragma unroll
    for (int fc = 0; fc < 4; ++fc)
      acc[3][fc] = __builtin_amdgcn_mfma_f32_16x16x32_f16(af1, bf[fc], acc[3][fc], 0, 0, 0);
    asm volatile("s_barrier" ::: "memory");

    // ---- sub-phase 2: A rows 4,5 ----
    if (pf) gload16(BgR0 + kq, Bpf + ldsl0);
    af0 = *(const f16x8*)(Ab + (wm * 128 + 4 * 16 + cc) * 32 + sc8);
    af1 = *(const f16x8*)(Ab + (wm * 128 + 5 * 16 + cc) * 32 + sc8);
#pragma unroll
    for (int fc = 0; fc < 4; ++fc)
      acc[4][fc] = __builtin_amdgcn_mfma_f32_16x16x32_f16(af0, bf[fc], acc[4][fc], 0, 0, 0);
#pragma unroll
    for (int fc = 0; fc < 4; ++fc)
      acc[5][fc] = __builtin_amdgcn_mfma_f32_16x16x32_f16(af1, bf[fc], acc[5][fc], 0, 0, 0);
    asm volatile("s_barrier" ::: "memory");

    // ---- sub-phase 3: A rows 6,7 ----
    if (pf) gload16(BgR1 + kq, Bpf + ldsl1);
    af0 = *(const f16x8*)(Ab + (wm * 128 + 6 * 16 + cc) * 32 + sc8);
    af1 = *(const f16x8*)(Ab + (wm * 128 + 7 * 16 + cc) * 32 + sc8);
#pragma unroll
    for (int fc = 0; fc < 4; ++fc)
      acc[6][fc] = __builtin_amdgcn_mfma_f32_16x16x32_f16(af0, bf[fc], acc[6][fc], 0, 0, 0);
#pragma unroll
    for (int fc = 0; fc < 4; ++fc)
      acc[7][fc] = __builtin_amdgcn_mfma_f32_16x16x32_f16(af1, bf[fc], acc[7][fc], 0, 0, 0);
    // no trailing barrier: next iteration's wait+barrier covers it
  }

  // epilogue
#pragma unroll
  for (int fr = 0; fr < 8; ++fr) {
    const int row = m0 + wm * 128 + fr * 16 + quad * 4;
#pragma unroll
    for (int fc = 0; fc < 4; ++fc) {
      const int col = n0 + wn * 64 + fc * 16 + cc;
#pragma unroll
      for (int r = 0; r < 4; ++r) {
        const size_t idx = (size_t)(row + r) * N + col;
        if (MODE == 1) unsafeAtomicAdd(&Cf[idx], acc[fr][fc][r]);
        else Ch[idx] = (f16)acc[fr][fc][r];
      }
    }
  }
}

// ---------------- GEMM (legacy 128x128): C[M,N](+)= A[M,K] (f16) @ BT[N,K]^T ----------------
template <int MODE>
__global__ __launch_bounds__(256) void gemm_bt(const f16* __restrict__ A,
                                               const f16* __restrict__ BT,
                                               float* __restrict__ Cf,
                                               f16* __restrict__ Ch,
                                               int N, int Ktot, int Kc) {
  __shared__ __attribute__((aligned(16))) f16 As[128 * 32];
  __shared__ __attribute__((aligned(16))) f16 Bs[128 * 32];
  const int tid = threadIdx.x;
  const int w = tid >> 6, lane = tid & 63;
  const int quad = lane >> 4, cc = lane & 15;
  const int wm = w >> 1, wn = w & 1;
  const int m0 = blockIdx.y * 128, n0 = blockIdx.x * 128;
  const int kbase = blockIdx.z * Kc;

  const int c1 = tid, c2 = tid + 256;
  const f16* Ag1 = A + (size_t)(m0 + (c1 >> 2)) * Ktot + kbase + (c1 & 3) * 8;
  const f16* Ag2 = A + (size_t)(m0 + (c2 >> 2)) * Ktot + kbase + (c2 & 3) * 8;
  const f16* Bg1 = BT + (size_t)(n0 + (c1 >> 2)) * Ktot + kbase + (c1 & 3) * 8;
  const f16* Bg2 = BT + (size_t)(n0 + (c2 >> 2)) * Ktot + kbase + (c2 & 3) * 8;
  f16* Al1 = As + (w * 64) * 8;
  f16* Al2 = As + (256 + w * 64) * 8;
  f16* Bl1 = Bs + (w * 64) * 8;
  f16* Bl2 = Bs + (256 + w * 64) * 8;

  const f32x4 fz = {0.f, 0.f, 0.f, 0.f};
  f32x4 acc[4][4];
#pragma unroll
  for (int i = 0; i < 4; ++i)
#pragma unroll
    for (int j = 0; j < 4; ++j) acc[i][j] = fz;

  for (int k0 = 0; k0 < Kc; k0 += 32) {
    __syncthreads();
    gload16(Ag1 + k0, Al1);
    gload16(Ag2 + k0, Al2);
    gload16(Bg1 + k0, Bl1);
    gload16(Bg2 + k0, Bl2);
    __syncthreads();
    f16x8 af[4], bf[4];
#pragma unroll
    for (int i = 0; i < 4; ++i)
      af[i] = *(const f16x8*)(As + (wm * 64 + i * 16 + cc) * 32 + quad * 8);
#pragma unroll
    for (int j = 0; j < 4; ++j)
      bf[j] = *(const f16x8*)(Bs + (wn * 64 + j * 16 + cc) * 32 + quad * 8);
#pragma unroll
    for (int i = 0; i < 4; ++i)
#pragma unroll
      for (int j = 0; j < 4; ++j)
        acc[i][j] = __builtin_amdgcn_mfma_f32_16x16x32_f16(af[i], bf[j], acc[i][j], 0, 0, 0);
  }

#pragma unroll
  for (int i = 0; i < 4; ++i) {
    const int row = m0 + wm * 64 + i * 16 + quad * 4;
#pragma unroll
    for (int j = 0; j < 4; ++j) {
      const int col = n0 + wn * 64 + j * 16 + cc;
#pragma unroll
      for (int r = 0; r < 4; ++r) {
        const size_t idx = (size_t)(row + r) * N + col;
        if (MODE == 1) unsafeAtomicAdd(&Cf[idx], acc[i][j][r]);
        else Ch[idx] = (f16)acc[i][j][r];
      }
    }
  }
}

// ---------------- transpose + f32->f16: src[K_][N_] f32 -> dst[N_][K_] f16 ----------------
__global__ __launch_bounds__(256) void transpose_f2h(const float* __restrict__ src,
                                                     f16* __restrict__ dst,
                                                     int K_, int N_) {
  __shared__ float tile[32][33];
  const int c0 = blockIdx.x * 32, r0 = blockIdx.y * 32;
  const int x = threadIdx.x & 31, y4 = threadIdx.x >> 5;
#pragma unroll
  for (int i = 0; i < 4; ++i) {
    int r = r0 + y4 + i * 8;
    if (r < K_ && c0 + x < N_) tile[y4 + i * 8][x] = src[(size_t)r * N_ + c0 + x];
  }
  __syncthreads();
#pragma unroll
  for (int i = 0; i < 4; ++i) {
    int rr = y4 + i * 8;
    int dr = c0 + rr, dc = r0 + x;
    if (dr < N_ && dc < K_) dst[(size_t)dr * K_ + dc] = (f16)tile[x][rr];
  }
}

// ---------------- RMSNorm ----------------
template <bool OUT_F32>
__global__ __launch_bounds__(256) void rmsnorm_kernel(const float* __restrict__ x,
                                                      const float* __restrict__ w,
                                                      f16* __restrict__ hh,
                                                      float* __restrict__ hf) {
  const int s = blockIdx.x;
  const float* xr = x + (size_t)s * H_DIM;
  float ss = 0.f;
  for (int i = threadIdx.x; i < H_DIM; i += 256) {
    float v = xr[i];
    ss += v * v;
  }
#pragma unroll
  for (int m = 32; m >= 1; m >>= 1) ss += __shfl_xor(ss, m);
  __shared__ float red[4];
  if ((threadIdx.x & 63) == 0) red[threadIdx.x >> 6] = ss;
  __syncthreads();
  ss = red[0] + red[1] + red[2] + red[3];
  const float rr = rsqrtf(ss * (1.0f / H_DIM) + 1e-6f);
  for (int i = threadIdx.x; i < H_DIM; i += 256) {
    float v = xr[i] * rr * w[i];
    if (OUT_F32) hf[(size_t)s * H_DIM + i] = v;
    else hh[(size_t)s * H_DIM + i] = (f16)v;
  }
}

// ---------------- RoPE + bias + layout split ----------------
__global__ __launch_bounds__(256) void rope_kernel(const float* __restrict__ qkv,
                                                   const float* __restrict__ cosb,
                                                   const float* __restrict__ sinb,
                                                   const float* __restrict__ bq,
                                                   const float* __restrict__ bk,
                                                   const float* __restrict__ bv,
                                                   f16* __restrict__ q_r,
                                                   f16* __restrict__ k_r,
                                                   f16* __restrict__ v_r) {
  const int s = blockIdx.x;
  const float* row = qkv + (size_t)s * QKV_N;
#pragma unroll
  for (int ci = 0; ci < 8; ++ci) {
    const int col = ci * 256 + threadIdx.x;
    if (col < 1536) {
      const int hh = col >> 7, d = col & 127;
      const int part = (d < 64) ? d + 64 : d - 64;
      const float v0 = row[col] + bq[col];
      const float v1 = row[(hh << 7) + part] + bq[(hh << 7) + part];
      const float cs = cosb[s * HD + d], sn = sinb[s * HD + d];
      const float rot = (d < 64) ? -v1 : v1;
      q_r[((size_t)hh * S_LEN + s) * HD + d] = (f16)(v0 * cs + rot * sn);
    } else if (col < 1792) {
      const int cc2 = col - 1536;
      const int hh = cc2 >> 7, d = cc2 & 127;
      const int part = (d < 64) ? d + 64 : d - 64;
      const float v0 = row[col] + bk[cc2];
      const float v1 = row[1536 + (hh << 7) + part] + bk[(hh << 7) + part];
      const float cs = cosb[s * HD + d], sn = sinb[s * HD + d];
      const float rot = (d < 64) ? -v1 : v1;
      k_r[((size_t)hh * S_LEN + s) * HD + d] = (f16)(v0 * cs + rot * sn);
    } else {
      const int cc2 = col - 1792;
      const int hh = cc2 >> 7, d = cc2 & 127;
      const float v0 = row[col] + bv[cc2];
      v_r[((size_t)hh * HD + d) * S_LEN + s] = (f16)v0;
    }
  }
}

// ---------------- fused flash attention (64-row Q tiles) ----------------
__global__ __launch_bounds__(256) void attn_kernel(const f16* __restrict__ Q,
                                                   const f16* __restrict__ Kc,
                                                   const f16* __restrict__ Vt,
                                                   f16* __restrict__ Oa) {
  __shared__ __attribute__((aligned(16))) f16 ks[64 * 136];
  __shared__ __attribute__((aligned(16))) f16 vs[128 * 72];
  __shared__ __attribute__((aligned(16))) f16 ps[64 * 72];
  const int h = blockIdx.x, qt = blockIdx.y;
  const int hk = h / (NQ_H / NKV_H);
  const int tid = threadIdx.x, w = tid >> 6, lane = tid & 63;
  const int quad = lane >> 4, cc = lane & 15;

  f16x8 qf[4];
  const f16* Qg = Q + ((size_t)h * S_LEN + qt * 64) * HD;
#pragma unroll
  for (int kk = 0; kk < 4; ++kk)
    qf[kk] = *(const f16x8*)(Qg + (size_t)(w * 16 + cc) * HD + kk * 32 + quad * 8);

  const f32x4 fz = {0.f, 0.f, 0.f, 0.f};
  f32x4 o_acc[8];
  float m_run[4], l_run[4];
#pragma unroll
  for (int j = 0; j < 8; ++j) o_acc[j] = fz;
#pragma unroll
  for (int r = 0; r < 4; ++r) { m_run[r] = -1e30f; l_run[r] = 0.f; }

  const int nkt = qt + 1;
  for (int kt = 0; kt < nkt; ++kt) {
    const int kv0 = kt * 64;
    __syncthreads();
    const f16* Kg = Kc + ((size_t)hk * S_LEN + kv0) * HD;
    for (int t = tid; t < 64 * 16; t += 256) {
      int r = t >> 4, ch = t & 15;
      *(uint4*)(ks + r * 136 + ch * 8) = *(const uint4*)(Kg + (size_t)r * HD + ch * 8);
    }
    const f16* Vg = Vt + (size_t)hk * HD * S_LEN + kv0;
    for (int t = tid; t < 128 * 8; t += 256) {
      int r = t >> 3, ch = t & 7;
      *(uint4*)(vs + r * 72 + ch * 8) = *(const uint4*)(Vg + (size_t)r * S_LEN + ch * 8);
    }
    __syncthreads();

    f32x4 sc[4];
#pragma unroll
    for (int j = 0; j < 4; ++j) sc[j] = fz;
#pragma unroll
    for (int kk = 0; kk < 4; ++kk) {
      f16x8 bfr[4];
#pragma unroll
      for (int j = 0; j < 4; ++j)
        bfr[j] = *(const f16x8*)(ks + (j * 16 + cc) * 136 + kk * 32 + quad * 8);
#pragma unroll
      for (int j = 0; j < 4; ++j)
        sc[j] = __builtin_amdgcn_mfma_f32_16x16x32_f16(qf[kk], bfr[j], sc[j], 0, 0, 0);
    }

    const bool need_mask = (kt == qt);
#pragma unroll
    for (int j = 0; j < 4; ++j)
#pragma unroll
      for (int r = 0; r < 4; ++r) {
        float v = sc[j][r] * SCALE;
        if (need_mask) {
          int rowg = qt * 64 + w * 16 + quad * 4 + r;
          int colg = kv0 + j * 16 + cc;
          if (colg > rowg) v = -1e30f;
        }
        sc[j][r] = v;
      }

#pragma unroll
    for (int r = 0; r < 4; ++r) {
      float mx = sc[0][r];
#pragma unroll
      for (int j = 1; j < 4; ++j) mx = fmaxf(mx, sc[j][r]);
      mx = fmaxf(mx, __shfl_xor(mx, 1));
      mx = fmaxf(mx, __shfl_xor(mx, 2));
      mx = fmaxf(mx, __shfl_xor(mx, 4));
      mx = fmaxf(mx, __shfl_xor(mx, 8));
      const float mnew = fmaxf(m_run[r], mx);
      const float alpha = __expf(m_run[r] - mnew);
      m_run[r] = mnew;
      l_run[r] *= alpha;
#pragma unroll
      for (int jd = 0; jd < 8; ++jd) o_acc[jd][r] *= alpha;
      float rs = 0.f;
      const int prow = w * 16 + quad * 4 + r;
#pragma unroll
      for (int j = 0; j < 4; ++j) {
        float p = __expf(sc[j][r] - mnew);
        rs += p;
        ps[prow * 72 + j * 16 + cc] = (f16)p;
      }
      rs += __shfl_xor(rs, 1);
      rs += __shfl_xor(rs, 2);
      rs += __shfl_xor(rs, 4);
      rs += __shfl_xor(rs, 8);
      l_run[r] += rs;
    }

#pragma unroll
    for (int kk = 0; kk < 2; ++kk) {
      f16x8 pa = *(const f16x8*)(ps + (w * 16 + cc) * 72 + kk * 32 + quad * 8);
#pragma unroll
      for (int j = 0; j < 8; ++j) {
        f16x8 vb = *(const f16x8*)(vs + (j * 16 + cc) * 72 + kk * 32 + quad * 8);
        o_acc[j] = __builtin_amdgcn_mfma_f32_16x16x32_f16(pa, vb, o_acc[j], 0, 0, 0);
      }
    }
  }

#pragma unroll
  for (int j = 0; j < 8; ++j)
#pragma unroll
    for (int r = 0; r < 4; ++r) {
      const int rowg = qt * 64 + w * 16 + quad * 4 + r;
      const int colg = j * 16 + cc;
      Oa[(size_t)rowg * H_DIM + h * HD + colg] = (f16)(o_acc[j][r] / l_run[r]);
    }
}

// ---------------- SiLU(gate) * up ----------------
__global__ __launch_bounds__(256) void silu_mul(const f16* __restrict__ gu,
                                                f16* __restrict__ hm) {
  const int i = blockIdx.x * 256 + threadIdx.x;
  const int s = blockIdx.y;
  const float g = (float)gu[(size_t)s * GU_N + i];
  const float u = (float)gu[(size_t)s * GU_N + I_DIM + i];
  const float sig = 1.f / (1.f + __expf(-g));
  hm[(size_t)s * I_DIM + i] = (f16)(g * sig * u);
}

extern "C" void kernel_launch(void* const* d_in, const int* in_sizes, int n_in,
                              void* d_out, int out_size, void* d_ws, size_t ws_size,
                              hipStream_t stream) {
  const float* hidden = (const float*)d_in[0];
  const float* cosb   = (const float*)d_in[1];
  const float* sinb   = (const float*)d_in[2];
  const float* Wq     = (const float*)d_in[4];
  const float* bq     = (const float*)d_in[5];
  const float* Wk     = (const float*)d_in[6];
  const float* bk     = (const float*)d_in[7];
  const float* Wv     = (const float*)d_in[8];
  const float* bv     = (const float*)d_in[9];
  const float* Wo     = (const float*)d_in[10];
  const float* Wg     = (const float*)d_in[11];
  const float* Wu     = (const float*)d_in[12];
  const float* Wd     = (const float*)d_in[13];
  const float* ln1    = (const float*)d_in[14];
  const float* ln2    = (const float*)d_in[15];
  const float* lnf    = (const float*)d_in[16];

  char* wp = (char*)d_ws;
  auto take = [&](size_t bytes) {
    void* p = (void*)wp;
    wp += (bytes + 255) & ~(size_t)255;
    return p;
  };
  f16* wqkvT  = (f16*)take((size_t)QKV_N * H_DIM * 2);
  f16* woT    = (f16*)take((size_t)H_DIM * H_DIM * 2);
  f16* wguT   = (f16*)take((size_t)GU_N * H_DIM * 2);
  f16* wdT    = (f16*)take((size_t)H_DIM * I_DIM * 2);
  float* x    = (float*)take((size_t)S_LEN * H_DIM * 4);
  f16* hbuf   = (f16*)take((size_t)S_LEN * H_DIM * 2);
  float* qkv  = (float*)take((size_t)S_LEN * QKV_N * 4);
  f16* q_r    = (f16*)take((size_t)NQ_H * S_LEN * HD * 2);
  f16* k_r    = (f16*)take((size_t)NKV_H * S_LEN * HD * 2);
  f16* v_r    = (f16*)take((size_t)NKV_H * HD * S_LEN * 2);
  f16* gu     = (f16*)take((size_t)S_LEN * GU_N * 2);
  f16* hmid   = (f16*)take((size_t)S_LEN * I_DIM * 2);

  hipMemcpyAsync(x, hidden, (size_t)S_LEN * H_DIM * 4, hipMemcpyDeviceToDevice, stream);

  for (int l = 0; l < 4; ++l) {
    transpose_f2h<<<dim3(48, 48), 256, 0, stream>>>(Wq + (size_t)l * H_DIM * 1536, wqkvT, H_DIM, 1536);
    transpose_f2h<<<dim3(8, 48), 256, 0, stream>>>(Wk + (size_t)l * H_DIM * 256, wqkvT + (size_t)1536 * H_DIM, H_DIM, 256);
    transpose_f2h<<<dim3(8, 48), 256, 0, stream>>>(Wv + (size_t)l * H_DIM * 256, wqkvT + (size_t)1792 * H_DIM, H_DIM, 256);
    transpose_f2h<<<dim3(48, 48), 256, 0, stream>>>(Wo + (size_t)l * H_DIM * H_DIM, woT, H_DIM, H_DIM);
    transpose_f2h<<<dim3(280, 48), 256, 0, stream>>>(Wg + (size_t)l * H_DIM * I_DIM, wguT, H_DIM, I_DIM);
    transpose_f2h<<<dim3(280, 48), 256, 0, stream>>>(Wu + (size_t)l * H_DIM * I_DIM, wguT + (size_t)I_DIM * H_DIM, H_DIM, I_DIM);
    transpose_f2h<<<dim3(48, 280), 256, 0, stream>>>(Wd + (size_t)l * I_DIM * H_DIM, wdT, I_DIM, H_DIM);

    rmsnorm_kernel<false><<<S_LEN, 256, 0, stream>>>(x, ln1 + l * H_DIM, hbuf, nullptr);
    hipMemsetAsync(qkv, 0, (size_t)S_LEN * QKV_N * 4, stream);
    gemm256<1><<<dim3(QKV_N / 256, S_LEN / 256, 4), 512, 0, stream>>>(hbuf, wqkvT, qkv, nullptr, QKV_N, H_DIM, 384);
    rope_kernel<<<S_LEN, 256, 0, stream>>>(qkv, cosb, sinb, bq + l * 1536, bk + l * 256, bv + l * 256, q_r, k_r, v_r);
    attn_kernel<<<dim3(NQ_H, S_LEN / 64), 256, 0, stream>>>(q_r, k_r, v_r, hbuf);
    gemm_bt<1><<<dim3(H_DIM / 128, S_LEN / 128, 4), 256, 0, stream>>>(hbuf, woT, x, nullptr, H_DIM, H_DIM, 384);
    rmsnorm_kernel<false><<<S_LEN, 256, 0, stream>>>(x, ln2 + l * H_DIM, hbuf, nullptr);
    gemm256<2><<<dim3(GU_N / 256, S_LEN / 256, 1), 512, 0, stream>>>(hbuf, wguT, nullptr, gu, GU_N, H_DIM, H_DIM);
    silu_mul<<<dim3(I_DIM / 256, S_LEN), 256, 0, stream>>>(gu, hmid);
    gemm256<1><<<dim3(H_DIM / 256, S_LEN / 256, 5), 512, 0, stream>>>(hmid, wdT, x, nullptr, H_DIM, I_DIM, 1792);
  }
  rmsnorm_kernel<true><<<S_LEN, 256, 0, stream>>>(x, lnf, nullptr, (float*)d_out);
}

// Round 2
// 3086.234 us; speedup vs baseline: 1.1761x; 1.1761x over previous
//
#include <hip/hip_runtime.h>

#define S_LEN 2048
#define H_DIM 1536
#define NQ_H 12
#define NKV_H 2
#define HD 128
#define I_DIM 8960
#define QKV_N 2048
#define GU_N 17920
#define SCALE 0.08838834764831845f

typedef _Float16 f16;
typedef _Float16 f16x8 __attribute__((ext_vector_type(8)));
typedef float f32x4 __attribute__((ext_vector_type(4)));

__device__ __forceinline__ void gload16(const void* g, void* l) {
  __builtin_amdgcn_global_load_lds((__attribute__((address_space(1))) void*)g,
                                   (__attribute__((address_space(3))) void*)l,
                                   16, 0, 0);
}

// ---------------- GEMM 256x256 tile, BK=32, 4-deep LDS ring, counted vmcnt ----------------
// C[M,N](+)= A[M,K] (f16) @ BT[N,K]^T (f16). Split-K via blockIdx.z (range Kc).
// MODE 1: unsafeAtomicAdd into Cf (f32). MODE 2: Ch = acc (f16; requires gridDim.z==1).
// Schedule per K-tile: [counted vmcnt][barrier][12 ds_read][setprio(1) 32 MFMA setprio(0)]
// [stage tile t+3 at END of body]. One barrier per tile; compiler pipelines freely inside.
// LDS chunk swizzle: cell(row, c) holds logical chunk c ^ (row&3); gload_lds dest linear,
// source pre-swizzled (rule 21).
template <int MODE>
__global__ __launch_bounds__(512, 2) void gemm256(const f16* __restrict__ A,
                                                  const f16* __restrict__ BT,
                                                  float* __restrict__ Cf,
                                                  f16* __restrict__ Ch,
                                                  int N, int Ktot, int Kc) {
  constexpr int TS = 256 * 32;  // f16 elems per ring slot (one 256x32 tile)
  __shared__ __attribute__((aligned(16))) f16 As[4 * TS];
  __shared__ __attribute__((aligned(16))) f16 Bs[4 * TS];
  const int tid = threadIdx.x;
  const int w = tid >> 6, lane = tid & 63;
  const int quad = lane >> 4, cc = lane & 15;
  const int wm = w >> 2, wn = w & 3;  // 2 (M) x 4 (N) waves; per-wave 128x64 output
  const int m0 = blockIdx.y * 256, n0 = blockIdx.x * 256;
  const int kbase = blockIdx.z * Kc;
  const int NT = Kc >> 5;

  // staging: wave w owns rows [w*32, w*32+32) of both A and BT; 2 rounds of 16 rows.
  const int srow = lane >> 2;              // 0..15 (row within a 16-row round)
  const int schk = lane & 3;               // LDS chunk slot (linear dest)
  const int gchk = schk ^ (srow & 3);      // pre-swizzled global chunk
  const f16* Ag = A + (size_t)(m0 + w * 32 + srow) * Ktot + kbase + gchk * 8;
  const f16* Bg = BT + (size_t)(n0 + w * 32 + srow) * Ktot + kbase + gchk * 8;
  const int lb = (w * 32) * 32;            // wave's LDS band (f16 elems)

  // fragment read: logical chunk quad stored at slot quad ^ (row&3); row%4 == cc&3
  const int rs8 = (quad ^ (cc & 3)) * 8;

  const f32x4 fz = {0.f, 0.f, 0.f, 0.f};
  f32x4 acc[8][4];
#pragma unroll
  for (int i = 0; i < 8; ++i)
#pragma unroll
    for (int j = 0; j < 4; ++j) acc[i][j] = fz;

#define STAGE256(slot, tt)                                   \
  {                                                          \
    f16* Ad = As + (slot)*TS + lb;                           \
    f16* Bd = Bs + (slot)*TS + lb;                           \
    const int ko = (tt)*32;                                  \
    gload16(Ag + ko, Ad);                                    \
    gload16(Ag + ko + 16 * Ktot, Ad + 16 * 32);              \
    gload16(Bg + ko, Bd);                                    \
    gload16(Bg + ko + 16 * Ktot, Bd + 16 * 32);              \
  }

  // prologue: stage tiles 0..2 (12 loads/wave in flight)
  STAGE256(0, 0);
  STAGE256(1, 1);
  STAGE256(2, 2);

  for (int t = 0; t < NT; ++t) {
    // counted wait: retire tile t's 4 loads; keep t+1/t+2 (up to 8) in flight
    const int ahead = NT - 1 - t;
    if (ahead >= 2)      asm volatile("s_waitcnt vmcnt(8)" ::: "memory");
    else if (ahead == 1) asm volatile("s_waitcnt vmcnt(4)" ::: "memory");
    else                 asm volatile("s_waitcnt vmcnt(0)" ::: "memory");
    asm volatile("s_barrier" ::: "memory");

    const f16* Ab = As + (t & 3) * TS;
    const f16* Bb = Bs + (t & 3) * TS;

    // all fragment reads first (no gload before any ds_read inside the body)
    f16x8 bf[4], af[8];
#pragma unroll
    for (int nf = 0; nf < 4; ++nf)
      bf[nf] = *(const f16x8*)(Bb + (wn * 64 + nf * 16 + cc) * 32 + rs8);
#pragma unroll
    for (int mf = 0; mf < 8; ++mf)
      af[mf] = *(const f16x8*)(Ab + (wm * 128 + mf * 16 + cc) * 32 + rs8);

    __builtin_amdgcn_s_setprio(1);
#pragma unroll
    for (int mf = 0; mf < 8; ++mf)
#pragma unroll
      for (int nf = 0; nf < 4; ++nf)
        acc[mf][nf] = __builtin_amdgcn_mfma_f32_16x16x32_f16(af[mf], bf[nf], acc[mf][nf], 0, 0, 0);
    __builtin_amdgcn_s_setprio(0);

    // stage tile t+3 at END of body: no ds_read follows it -> no alias serialization
    if (t + 3 < NT) STAGE256((t + 3) & 3, t + 3);
  }
#undef STAGE256

  // epilogue
#pragma unroll
  for (int fr = 0; fr < 8; ++fr) {
    const int row = m0 + wm * 128 + fr * 16 + quad * 4;
#pragma unroll
    for (int fc = 0; fc < 4; ++fc) {
      const int col = n0 + wn * 64 + fc * 16 + cc;
#pragma unroll
      for (int r = 0; r < 4; ++r) {
        const size_t idx = (size_t)(row + r) * N + col;
        if (MODE == 1) unsafeAtomicAdd(&Cf[idx], acc[fr][fc][r]);
        else Ch[idx] = (f16)acc[fr][fc][r];
      }
    }
  }
}

// ---------------- GEMM (legacy 128x128): C[M,N](+)= A[M,K] (f16) @ BT[N,K]^T ----------------
template <int MODE>
__global__ __launch_bounds__(256) void gemm_bt(const f16* __restrict__ A,
                                               const f16* __restrict__ BT,
                                               float* __restrict__ Cf,
                                               f16* __restrict__ Ch,
                                               int N, int Ktot, int Kc) {
  __shared__ __attribute__((aligned(16))) f16 As[128 * 32];
  __shared__ __attribute__((aligned(16))) f16 Bs[128 * 32];
  const int tid = threadIdx.x;
  const int w = tid >> 6, lane = tid & 63;
  const int quad = lane >> 4, cc = lane & 15;
  const int wm = w >> 1, wn = w & 1;
  const int m0 = blockIdx.y * 128, n0 = blockIdx.x * 128;
  const int kbase = blockIdx.z * Kc;

  const int c1 = tid, c2 = tid + 256;
  const f16* Ag1 = A + (size_t)(m0 + (c1 >> 2)) * Ktot + kbase + (c1 & 3) * 8;
  const f16* Ag2 = A + (size_t)(m0 + (c2 >> 2)) * Ktot + kbase + (c2 & 3) * 8;
  const f16* Bg1 = BT + (size_t)(n0 + (c1 >> 2)) * Ktot + kbase + (c1 & 3) * 8;
  const f16* Bg2 = BT + (size_t)(n0 + (c2 >> 2)) * Ktot + kbase + (c2 & 3) * 8;
  f16* Al1 = As + (w * 64) * 8;
  f16* Al2 = As + (256 + w * 64) * 8;
  f16* Bl1 = Bs + (w * 64) * 8;
  f16* Bl2 = Bs + (256 + w * 64) * 8;

  const f32x4 fz = {0.f, 0.f, 0.f, 0.f};
  f32x4 acc[4][4];
#pragma unroll
  for (int i = 0; i < 4; ++i)
#pragma unroll
    for (int j = 0; j < 4; ++j) acc[i][j] = fz;

  for (int k0 = 0; k0 < Kc; k0 += 32) {
    __syncthreads();
    gload16(Ag1 + k0, Al1);
    gload16(Ag2 + k0, Al2);
    gload16(Bg1 + k0, Bl1);
    gload16(Bg2 + k0, Bl2);
    __syncthreads();
    f16x8 af[4], bf[4];
#pragma unroll
    for (int i = 0; i < 4; ++i)
      af[i] = *(const f16x8*)(As + (wm * 64 + i * 16 + cc) * 32 + quad * 8);
#pragma unroll
    for (int j = 0; j < 4; ++j)
      bf[j] = *(const f16x8*)(Bs + (wn * 64 + j * 16 + cc) * 32 + quad * 8);
#pragma unroll
    for (int i = 0; i < 4; ++i)
#pragma unroll
      for (int j = 0; j < 4; ++j)
        acc[i][j] = __builtin_amdgcn_mfma_f32_16x16x32_f16(af[i], bf[j], acc[i][j], 0, 0, 0);
  }

#pragma unroll
  for (int i = 0; i < 4; ++i) {
    const int row = m0 + wm * 64 + i * 16 + quad * 4;
#pragma unroll
    for (int j = 0; j < 4; ++j) {
      const int col = n0 + wn * 64 + j * 16 + cc;
#pragma unroll
      for (int r = 0; r < 4; ++r) {
        const size_t idx = (size_t)(row + r) * N + col;
        if (MODE == 1) unsafeAtomicAdd(&Cf[idx], acc[i][j][r]);
        else Ch[idx] = (f16)acc[i][j][r];
      }
    }
  }
}

// ---------------- transpose + f32->f16: src[K_][N_] f32 -> dst[N_][K_] f16 ----------------
__global__ __launch_bounds__(256) void transpose_f2h(const float* __restrict__ src,
                                                     f16* __restrict__ dst,
                                                     int K_, int N_) {
  __shared__ float tile[32][33];
  const int c0 = blockIdx.x * 32, r0 = blockIdx.y * 32;
  const int x = threadIdx.x & 31, y4 = threadIdx.x >> 5;
#pragma unroll
  for (int i = 0; i < 4; ++i) {
    int r = r0 + y4 + i * 8;
    if (r < K_ && c0 + x < N_) tile[y4 + i * 8][x] = src[(size_t)r * N_ + c0 + x];
  }
  __syncthreads();
#pragma unroll
  for (int i = 0; i < 4; ++i) {
    int rr = y4 + i * 8;
    int dr = c0 + rr, dc = r0 + x;
    if (dr < N_ && dc < K_) dst[(size_t)dr * K_ + dc] = (f16)tile[x][rr];
  }
}

// ---------------- RMSNorm ----------------
template <bool OUT_F32>
__global__ __launch_bounds__(256) void rmsnorm_kernel(const float* __restrict__ x,
                                                      const float* __restrict__ w,
                                                      f16* __restrict__ hh,
                                                      float* __restrict__ hf) {
  const int s = blockIdx.x;
  const float* xr = x + (size_t)s * H_DIM;
  float ss = 0.f;
  for (int i = threadIdx.x; i < H_DIM; i += 256) {
    float v = xr[i];
    ss += v * v;
  }
#pragma unroll
  for (int m = 32; m >= 1; m >>= 1) ss += __shfl_xor(ss, m);
  __shared__ float red[4];
  if ((threadIdx.x & 63) == 0) red[threadIdx.x >> 6] = ss;
  __syncthreads();
  ss = red[0] + red[1] + red[2] + red[3];
  const float rr = rsqrtf(ss * (1.0f / H_DIM) + 1e-6f);
  for (int i = threadIdx.x; i < H_DIM; i += 256) {
    float v = xr[i] * rr * w[i];
    if (OUT_F32) hf[(size_t)s * H_DIM + i] = v;
    else hh[(size_t)s * H_DIM + i] = (f16)v;
  }
}

// ---------------- RoPE + bias + layout split ----------------
__global__ __launch_bounds__(256) void rope_kernel(const float* __restrict__ qkv,
                                                   const float* __restrict__ cosb,
                                                   const float* __restrict__ sinb,
                                                   const float* __restrict__ bq,
                                                   const float* __restrict__ bk,
                                                   const float* __restrict__ bv,
                                                   f16* __restrict__ q_r,
                                                   f16* __restrict__ k_r,
                                                   f16* __restrict__ v_r) {
  const int s = blockIdx.x;
  const float* row = qkv + (size_t)s * QKV_N;
#pragma unroll
  for (int ci = 0; ci < 8; ++ci) {
    const int col = ci * 256 + threadIdx.x;
    if (col < 1536) {
      const int hh = col >> 7, d = col & 127;
      const int part = (d < 64) ? d + 64 : d - 64;
      const float v0 = row[col] + bq[col];
      const float v1 = row[(hh << 7) + part] + bq[(hh << 7) + part];
      const float cs = cosb[s * HD + d], sn = sinb[s * HD + d];
      const float rot = (d < 64) ? -v1 : v1;
      q_r[((size_t)hh * S_LEN + s) * HD + d] = (f16)(v0 * cs + rot * sn);
    } else if (col < 1792) {
      const int cc2 = col - 1536;
      const int hh = cc2 >> 7, d = cc2 & 127;
      const int part = (d < 64) ? d + 64 : d - 64;
      const float v0 = row[col] + bk[cc2];
      const float v1 = row[1536 + (hh << 7) + part] + bk[(hh << 7) + part];
      const float cs = cosb[s * HD + d], sn = sinb[s * HD + d];
      const float rot = (d < 64) ? -v1 : v1;
      k_r[((size_t)hh * S_LEN + s) * HD + d] = (f16)(v0 * cs + rot * sn);
    } else {
      const int cc2 = col - 1792;
      const int hh = cc2 >> 7, d = cc2 & 127;
      const float v0 = row[col] + bv[cc2];
      v_r[((size_t)hh * HD + d) * S_LEN + s] = (f16)v0;
    }
  }
}

// ---------------- fused flash attention (64-row Q tiles) ----------------
__global__ __launch_bounds__(256) void attn_kernel(const f16* __restrict__ Q,
                                                   const f16* __restrict__ Kc,
                                                   const f16* __restrict__ Vt,
                                                   f16* __restrict__ Oa) {
  __shared__ __attribute__((aligned(16))) f16 ks[64 * 136];
  __shared__ __attribute__((aligned(16))) f16 vs[128 * 72];
  __shared__ __attribute__((aligned(16))) f16 ps[64 * 72];
  const int h = blockIdx.x, qt = blockIdx.y;
  const int hk = h / (NQ_H / NKV_H);
  const int tid = threadIdx.x, w = tid >> 6, lane = tid & 63;
  const int quad = lane >> 4, cc = lane & 15;

  f16x8 qf[4];
  const f16* Qg = Q + ((size_t)h * S_LEN + qt * 64) * HD;
#pragma unroll
  for (int kk = 0; kk < 4; ++kk)
    qf[kk] = *(const f16x8*)(Qg + (size_t)(w * 16 + cc) * HD + kk * 32 + quad * 8);

  const f32x4 fz = {0.f, 0.f, 0.f, 0.f};
  f32x4 o_acc[8];
  float m_run[4], l_run[4];
#pragma unroll
  for (int j = 0; j < 8; ++j) o_acc[j] = fz;
#pragma unroll
  for (int r = 0; r < 4; ++r) { m_run[r] = -1e30f; l_run[r] = 0.f; }

  const int nkt = qt + 1;
  for (int kt = 0; kt < nkt; ++kt) {
    const int kv0 = kt * 64;
    __syncthreads();
    const f16* Kg = Kc + ((size_t)hk * S_LEN + kv0) * HD;
    for (int t = tid; t < 64 * 16; t += 256) {
      int r = t >> 4, ch = t & 15;
      *(uint4*)(ks + r * 136 + ch * 8) = *(const uint4*)(Kg + (size_t)r * HD + ch * 8);
    }
    const f16* Vg = Vt + (size_t)hk * HD * S_LEN + kv0;
    for (int t = tid; t < 128 * 8; t += 256) {
      int r = t >> 3, ch = t & 7;
      *(uint4*)(vs + r * 72 + ch * 8) = *(const uint4*)(Vg + (size_t)r * S_LEN + ch * 8);
    }
    __syncthreads();

    f32x4 sc[4];
#pragma unroll
    for (int j = 0; j < 4; ++j) sc[j] = fz;
#pragma unroll
    for (int kk = 0; kk < 4; ++kk) {
      f16x8 bfr[4];
#pragma unroll
      for (int j = 0; j < 4; ++j)
        bfr[j] = *(const f16x8*)(ks + (j * 16 + cc) * 136 + kk * 32 + quad * 8);
#pragma unroll
      for (int j = 0; j < 4; ++j)
        sc[j] = __builtin_amdgcn_mfma_f32_16x16x32_f16(qf[kk], bfr[j], sc[j], 0, 0, 0);
    }

    const bool need_mask = (kt == qt);
#pragma unroll
    for (int j = 0; j < 4; ++j)
#pragma unroll
      for (int r = 0; r < 4; ++r) {
        float v = sc[j][r] * SCALE;
        if (need_mask) {
          int rowg = qt * 64 + w * 16 + quad * 4 + r;
          int colg = kv0 + j * 16 + cc;
          if (colg > rowg) v = -1e30f;
        }
        sc[j][r] = v;
      }

#pragma unroll
    for (int r = 0; r < 4; ++r) {
      float mx = sc[0][r];
#pragma unroll
      for (int j = 1; j < 4; ++j) mx = fmaxf(mx, sc[j][r]);
      mx = fmaxf(mx, __shfl_xor(mx, 1));
      mx = fmaxf(mx, __shfl_xor(mx, 2));
      mx = fmaxf(mx, __shfl_xor(mx, 4));
      mx = fmaxf(mx, __shfl_xor(mx, 8));
      const float mnew = fmaxf(m_run[r], mx);
      const float alpha = __expf(m_run[r] - mnew);
      m_run[r] = mnew;
      l_run[r] *= alpha;
#pragma unroll
      for (int jd = 0; jd < 8; ++jd) o_acc[jd][r] *= alpha;
      float rs = 0.f;
      const int prow = w * 16 + quad * 4 + r;
#pragma unroll
      for (int j = 0; j < 4; ++j) {
        float p = __expf(sc[j][r] - mnew);
        rs += p;
        ps[prow * 72 + j * 16 + cc] = (f16)p;
      }
      rs += __shfl_xor(rs, 1);
      rs += __shfl_xor(rs, 2);
      rs += __shfl_xor(rs, 4);
      rs += __shfl_xor(rs, 8);
      l_run[r] += rs;
    }

#pragma unroll
    for (int kk = 0; kk < 2; ++kk) {
      f16x8 pa = *(const f16x8*)(ps + (w * 16 + cc) * 72 + kk * 32 + quad * 8);
#pragma unroll
      for (int j = 0; j < 8; ++j) {
        f16x8 vb = *(const f16x8*)(vs + (j * 16 + cc) * 72 + kk * 32 + quad * 8);
        o_acc[j] = __builtin_amdgcn_mfma_f32_16x16x32_f16(pa, vb, o_acc[j], 0, 0, 0);
      }
    }
  }

#pragma unroll
  for (int j = 0; j < 8; ++j)
#pragma unroll
    for (int r = 0; r < 4; ++r) {
      const int rowg = qt * 64 + w * 16 + quad * 4 + r;
      const int colg = j * 16 + cc;
      Oa[(size_t)rowg * H_DIM + h * HD + colg] = (f16)(o_acc[j][r] / l_run[r]);
    }
}

// ---------------- SiLU(gate) * up ----------------
__global__ __launch_bounds__(256) void silu_mul(const f16* __restrict__ gu,
                                                f16* __restrict__ hm) {
  const int i = blockIdx.x * 256 + threadIdx.x;
  const int s = blockIdx.y;
  const float g = (float)gu[(size_t)s * GU_N + i];
  const float u = (float)gu[(size_t)s * GU_N + I_DIM + i];
  const float sig = 1.f / (1.f + __expf(-g));
  hm[(size_t)s * I_DIM + i] = (f16)(g * sig * u);
}

extern "C" void kernel_launch(void* const* d_in, const int* in_sizes, int n_in,
                              void* d_out, int out_size, void* d_ws, size_t ws_size,
                              hipStream_t stream) {
  const float* hidden = (const float*)d_in[0];
  const float* cosb   = (const float*)d_in[1];
  const float* sinb   = (const float*)d_in[2];
  const float* Wq     = (const float*)d_in[4];
  const float* bq     = (const float*)d_in[5];
  const float* Wk     = (const float*)d_in[6];
  const float* bk     = (const float*)d_in[7];
  const float* Wv     = (const float*)d_in[8];
  const float* bv     = (const float*)d_in[9];
  const float* Wo     = (const float*)d_in[10];
  const float* Wg     = (const float*)d_in[11];
  const float* Wu     = (const float*)d_in[12];
  const float* Wd     = (const float*)d_in[13];
  const float* ln1    = (const float*)d_in[14];
  const float* ln2    = (const float*)d_in[15];
  const float* lnf    = (const float*)d_in[16];

  char* wp = (char*)d_ws;
  auto take = [&](size_t bytes) {
    void* p = (void*)wp;
    wp += (bytes + 255) & ~(size_t)255;
    return p;
  };
  f16* wqkvT  = (f16*)take((size_t)QKV_N * H_DIM * 2);
  f16* woT    = (f16*)take((size_t)H_DIM * H_DIM * 2);
  f16* wguT   = (f16*)take((size_t)GU_N * H_DIM * 2);
  f16* wdT    = (f16*)take((size_t)H_DIM * I_DIM * 2);
  float* x    = (float*)take((size_t)S_LEN * H_DIM * 4);
  f16* hbuf   = (f16*)take((size_t)S_LEN * H_DIM * 2);
  float* qkv  = (float*)take((size_t)S_LEN * QKV_N * 4);
  f16* q_r    = (f16*)take((size_t)NQ_H * S_LEN * HD * 2);
  f16* k_r    = (f16*)take((size_t)NKV_H * S_LEN * HD * 2);
  f16* v_r    = (f16*)take((size_t)NKV_H * HD * S_LEN * 2);
  f16* gu     = (f16*)take((size_t)S_LEN * GU_N * 2);
  f16* hmid   = (f16*)take((size_t)S_LEN * I_DIM * 2);

  hipMemcpyAsync(x, hidden, (size_t)S_LEN * H_DIM * 4, hipMemcpyDeviceToDevice, stream);

  for (int l = 0; l < 4; ++l) {
    transpose_f2h<<<dim3(48, 48), 256, 0, stream>>>(Wq + (size_t)l * H_DIM * 1536, wqkvT, H_DIM, 1536);
    transpose_f2h<<<dim3(8, 48), 256, 0, stream>>>(Wk + (size_t)l * H_DIM * 256, wqkvT + (size_t)1536 * H_DIM, H_DIM, 256);
    transpose_f2h<<<dim3(8, 48), 256, 0, stream>>>(Wv + (size_t)l * H_DIM * 256, wqkvT + (size_t)1792 * H_DIM, H_DIM, 256);
    transpose_f2h<<<dim3(48, 48), 256, 0, stream>>>(Wo + (size_t)l * H_DIM * H_DIM, woT, H_DIM, H_DIM);
    transpose_f2h<<<dim3(280, 48), 256, 0, stream>>>(Wg + (size_t)l * H_DIM * I_DIM, wguT, H_DIM, I_DIM);
    transpose_f2h<<<dim3(280, 48), 256, 0, stream>>>(Wu + (size_t)l * H_DIM * I_DIM, wguT + (size_t)I_DIM * H_DIM, H_DIM, I_DIM);
    transpose_f2h<<<dim3(48, 280), 256, 0, stream>>>(Wd + (size_t)l * I_DIM * H_DIM, wdT, I_DIM, H_DIM);

    rmsnorm_kernel<false><<<S_LEN, 256, 0, stream>>>(x, ln1 + l * H_DIM, hbuf, nullptr);
    hipMemsetAsync(qkv, 0, (size_t)S_LEN * QKV_N * 4, stream);
    gemm256<1><<<dim3(QKV_N / 256, S_LEN / 256, 4), 512, 0, stream>>>(hbuf, wqkvT, qkv, nullptr, QKV_N, H_DIM, 384);
    rope_kernel<<<S_LEN, 256, 0, stream>>>(qkv, cosb, sinb, bq + l * 1536, bk + l * 256, bv + l * 256, q_r, k_r, v_r);
    attn_kernel<<<dim3(NQ_H, S_LEN / 64), 256, 0, stream>>>(q_r, k_r, v_r, hbuf);
    gemm_bt<1><<<dim3(H_DIM / 128, S_LEN / 128, 4), 256, 0, stream>>>(hbuf, woT, x, nullptr, H_DIM, H_DIM, 384);
    rmsnorm_kernel<false><<<S_LEN, 256, 0, stream>>>(x, ln2 + l * H_DIM, hbuf, nullptr);
    gemm256<2><<<dim3(GU_N / 256, S_LEN / 256, 1), 512, 0, stream>>>(hbuf, wguT, nullptr, gu, GU_N, H_DIM, H_DIM);
    silu_mul<<<dim3(I_DIM / 256, S_LEN), 256, 0, stream>>>(gu, hmid);
    gemm256<1><<<dim3(H_DIM / 256, S_LEN / 256, 5), 512, 0, stream>>>(hmid, wdT, x, nullptr, H_DIM, I_DIM, 1792);
  }
  rmsnorm_kernel<true><<<S_LEN, 256, 0, stream>>>(x, lnf, nullptr, (float*)d_out);
}